// Round 1
// baseline (314.076 us; speedup 1.0000x reference)
//
#include <hip/hip_runtime.h>

// ws layout:
//   u32 scal[0]: maxabs(x)     (f32 bits, atomicMax as u32 — values >= 0)
//   u32 scal[1]: maxabs(conv_w) (f32 bits)
//   u32 scal[2]: maxabs(fc_w)   (f32 bits)
//   u32 scal[3]: maxabs(flat)   (f32 bits, atomicMax as u32)
//   byte 256+ : flat buffer, 8192*576 f32 = 18,874,368 B

#define DEV __device__ __forceinline__

// IEEE-exact quant index: clip(v/s, -7, 7) then round-half-even.
// MUST use true division (correctly rounded) to bit-match the reference;
// reciprocal-multiply can flip round-to-nearest-even ties.
DEV float quantq(float v, float s) {
  return rintf(fminf(7.0f, fmaxf(-7.0f, v / s)));
}

DEV float block_reduce_max(float v, float* smem) {
#pragma unroll
  for (int off = 32; off > 0; off >>= 1)
    v = fmaxf(v, __shfl_xor(v, off, 64));
  __syncthreads();  // protect smem against reuse across calls
  if ((threadIdx.x & 63) == 0) smem[threadIdx.x >> 6] = v;
  __syncthreads();
  float m = smem[0];
  for (int i = 1; i < ((int)blockDim.x >> 6); ++i) m = fmaxf(m, smem[i]);
  return m;
}

// One block: weight max-abs reductions + zero the atomic slots.
__global__ __launch_bounds__(256) void prep_kernel(
    const float* __restrict__ cw, const float* __restrict__ fw,
    unsigned int* __restrict__ scal) {
  __shared__ float smem[8];
  const int tid = threadIdx.x;
  float m1 = 0.f;
  for (int i = tid; i < 144; i += 256) m1 = fmaxf(m1, fabsf(cw[i]));
  m1 = block_reduce_max(m1, smem);
  float m2 = 0.f;
  for (int i = tid; i < 5760; i += 256) m2 = fmaxf(m2, fabsf(fw[i]));
  m2 = block_reduce_max(m2, smem);
  if (tid == 0) {
    scal[0] = 0u;  // 0.0f bits
    scal[1] = __float_as_uint(m1);
    scal[2] = __float_as_uint(m2);
    scal[3] = 0u;
  }
}

__global__ __launch_bounds__(256) void maxabs_x_kernel(
    const float4* __restrict__ x4, int n4, unsigned int* __restrict__ scal) {
  __shared__ float smem[8];
  float m = 0.f;
  for (int i = blockIdx.x * blockDim.x + threadIdx.x; i < n4;
       i += gridDim.x * blockDim.x) {
    float4 v = x4[i];
    m = fmaxf(m, fmaxf(fmaxf(fabsf(v.x), fabsf(v.y)),
                       fmaxf(fabsf(v.z), fabsf(v.w))));
  }
  m = block_reduce_max(m, smem);
  if (threadIdx.x == 0) atomicMax(scal + 0, __float_as_uint(m));
}

// One block per image: quantize x -> LDS, conv(3x3,16ch) + bias + relu +
// maxpool(4x4) + flatten; also block-reduce max|flat| -> atomicMax.
// Integer-valued f32 conv accumulation is exact (|sum| <= 441).
__global__ __launch_bounds__(256) void conv_pool_kernel(
    const float* __restrict__ x, const float* __restrict__ cw,
    const float* __restrict__ cb, unsigned int* __restrict__ scal,
    float* __restrict__ flat) {
  __shared__ float qx[784];
  __shared__ float qw[16][9];
  __shared__ float bias[16];
  __shared__ float smem[8];
  const int b = blockIdx.x, tid = threadIdx.x;
  const float sx = __uint_as_float(scal[0]) / 7.0f + 1e-8f;
  const float sw = __uint_as_float(scal[1]) / 7.0f + 1e-8f;
  const float sxw = sx * sw;
  for (int i = tid; i < 784; i += 256) qx[i] = quantq(x[b * 784 + i], sx);
  if (tid < 144) qw[tid / 9][tid % 9] = quantq(cw[tid], sw);
  if (tid < 16) bias[tid] = cb[tid];
  __syncthreads();
  float lmax = 0.f;
  for (int f = tid; f < 576; f += 256) {
    const int c = f / 36, rem = f % 36, pi = rem / 6, pj = rem % 6;
    const float w0 = qw[c][0], w1 = qw[c][1], w2 = qw[c][2];
    const float w3 = qw[c][3], w4 = qw[c][4], w5 = qw[c][5];
    const float w6 = qw[c][6], w7 = qw[c][7], w8 = qw[c][8];
    const float bc = bias[c];
    float m = 0.f;  // ReLU folded into pool-max (values clamped at 0)
#pragma unroll
    for (int dr = 0; dr < 4; ++dr) {
      const int r = 4 * pi + dr;
#pragma unroll
      for (int dc = 0; dc < 4; ++dc) {
        const float* p = &qx[r * 28 + 4 * pj + dc];
        float acc = p[0] * w0 + p[1] * w1 + p[2] * w2
                  + p[28] * w3 + p[29] * w4 + p[30] * w5
                  + p[56] * w6 + p[57] * w7 + p[58] * w8;
        m = fmaxf(m, acc * sxw + bc);
      }
    }
    flat[b * 576 + f] = m;
    lmax = fmaxf(lmax, m);  // m >= 0, so m == |m|
  }
  lmax = block_reduce_max(lmax, smem);
  if (tid == 0) atomicMax(scal + 3, __float_as_uint(lmax));
}

// One thread per image; quantized fc_w staged in LDS (broadcast reads).
// Integer dot (<= 28224) exact in f32.
__global__ __launch_bounds__(256) void fc_kernel(
    const float* __restrict__ flat, const float* __restrict__ fw,
    const float* __restrict__ fb, const unsigned int* __restrict__ scal,
    float* __restrict__ out) {
  __shared__ float qfw[10][576];
  __shared__ float sb[10];
  const float sf = __uint_as_float(scal[3]) / 7.0f + 1e-8f;
  const float sfw = __uint_as_float(scal[2]) / 7.0f + 1e-8f;
  const int tid = threadIdx.x;
  for (int i = tid; i < 5760; i += 256) (&qfw[0][0])[i] = quantq(fw[i], sfw);
  if (tid < 10) sb[tid] = fb[tid];
  __syncthreads();
  const int b = blockIdx.x * 256 + tid;
  float acc[10];
#pragma unroll
  for (int o = 0; o < 10; ++o) acc[o] = 0.f;
  for (int k = 0; k < 576; ++k) {
    const float qf = quantq(flat[b * 576 + k], sf);
#pragma unroll
    for (int o = 0; o < 10; ++o) acc[o] += qf * qfw[o][k];
  }
  const float ss = sf * sfw;
#pragma unroll
  for (int o = 0; o < 10; ++o) out[b * 10 + o] = acc[o] * ss + sb[o];
}

extern "C" void kernel_launch(void* const* d_in, const int* in_sizes, int n_in,
                              void* d_out, int out_size, void* d_ws, size_t ws_size,
                              hipStream_t stream) {
  const float* x  = (const float*)d_in[0];
  const float* cw = (const float*)d_in[1];
  const float* cb = (const float*)d_in[2];
  const float* fw = (const float*)d_in[3];
  const float* fb = (const float*)d_in[4];
  float* out = (float*)d_out;
  unsigned int* scal = (unsigned int*)d_ws;
  float* flat = (float*)((char*)d_ws + 256);

  prep_kernel<<<1, 256, 0, stream>>>(cw, fw, scal);
  maxabs_x_kernel<<<1024, 256, 0, stream>>>(
      (const float4*)x, (8192 * 784) / 4, scal);
  conv_pool_kernel<<<8192, 256, 0, stream>>>(x, cw, cb, scal, flat);
  fc_kernel<<<32, 256, 0, stream>>>(flat, fw, fb, scal, out);
}

// Round 2
// 156.987 us; speedup vs baseline: 2.0006x; 2.0006x over previous
//
#include <hip/hip_runtime.h>

// ws layout:
//   u32 scal[0]: maxabs(x)      (f32 bits, atomicMax as u32 — values >= 0)
//   u32 scal[1]: maxabs(conv_w) (f32 bits)
//   u32 scal[2]: maxabs(fc_w)   (f32 bits)
//   u32 scal[3]: maxabs(flat)   (f32 bits, atomicMax as u32)
//   byte 256+ : flat buffer, 8192*576 f32 = 18,874,368 B

#define DEV __device__ __forceinline__

// IEEE-exact quant index: clip(v/s, -7, 7) then round-half-even.
// MUST use true division (correctly rounded) to bit-match the reference;
// reciprocal-multiply can flip round-to-nearest-even ties.
DEV float quantq(float v, float s) {
  return rintf(fminf(7.0f, fmaxf(-7.0f, v / s)));
}

DEV float block_reduce_max(float v, float* smem) {
#pragma unroll
  for (int off = 32; off > 0; off >>= 1)
    v = fmaxf(v, __shfl_xor(v, off, 64));
  __syncthreads();
  if ((threadIdx.x & 63) == 0) smem[threadIdx.x >> 6] = v;
  __syncthreads();
  float m = smem[0];
  for (int i = 1; i < ((int)blockDim.x >> 6); ++i) m = fmaxf(m, smem[i]);
  return m;
}

// One block: weight max-abs reductions + zero the atomic slots.
__global__ __launch_bounds__(256) void prep_kernel(
    const float* __restrict__ cw, const float* __restrict__ fw,
    unsigned int* __restrict__ scal) {
  __shared__ float smem[8];
  const int tid = threadIdx.x;
  float m1 = 0.f;
  for (int i = tid; i < 144; i += 256) m1 = fmaxf(m1, fabsf(cw[i]));
  m1 = block_reduce_max(m1, smem);
  float m2 = 0.f;
  for (int i = tid; i < 5760; i += 256) m2 = fmaxf(m2, fabsf(fw[i]));
  m2 = block_reduce_max(m2, smem);
  if (tid == 0) {
    scal[0] = 0u;
    scal[1] = __float_as_uint(m1);
    scal[2] = __float_as_uint(m2);
    scal[3] = 0u;
  }
}

__global__ __launch_bounds__(256) void maxabs_x_kernel(
    const float4* __restrict__ x4, int n4, unsigned int* __restrict__ scal) {
  __shared__ float smem[8];
  float m = 0.f;
  for (int i = blockIdx.x * blockDim.x + threadIdx.x; i < n4;
       i += gridDim.x * blockDim.x) {
    float4 v = x4[i];
    m = fmaxf(m, fmaxf(fmaxf(fabsf(v.x), fabsf(v.y)),
                       fmaxf(fabsf(v.z), fabsf(v.w))));
  }
  m = block_reduce_max(m, smem);
  if (threadIdx.x == 0) atomicMax(scal + 0, __float_as_uint(m));
}

// 7 images per block. Stage quantized x in LDS (float4), then one thread per
// (image, pooled-position): load the 6x6 patch into 36 registers ONCE and
// compute all 16 channels from registers (the input window is shared across
// channels). Conv accumulation is exact (integer-valued f32, |sum| <= 441).
// ReLU folded into pool-max (m starts at 0).
#define IMGS_PER_BLK 7
__global__ __launch_bounds__(256) void conv_pool_kernel(
    const float* __restrict__ x, const float* __restrict__ cw,
    const float* __restrict__ cb, unsigned int* __restrict__ scal,
    float* __restrict__ flat) {
  __shared__ __align__(16) float qx[IMGS_PER_BLK * 784];
  __shared__ float qw[16][9];
  __shared__ float bias[16];
  __shared__ float smem[8];
  const int tid = threadIdx.x;
  const int b0 = blockIdx.x * IMGS_PER_BLK;
  const int nimg = min(IMGS_PER_BLK, 8192 - b0);
  const float sx = __uint_as_float(scal[0]) / 7.0f + 1e-8f;
  const float sw = __uint_as_float(scal[1]) / 7.0f + 1e-8f;
  const float sxw = sx * sw;
  // stage + quantize input (784*4 bytes per image is 16B-aligned)
  {
    const float4* x4 = (const float4*)x + b0 * 196;
    float4* q4 = (float4*)qx;
    const int n4 = nimg * 196;
    for (int i = tid; i < n4; i += 256) {
      float4 v = x4[i];
      float4 q;
      q.x = quantq(v.x, sx); q.y = quantq(v.y, sx);
      q.z = quantq(v.z, sx); q.w = quantq(v.w, sx);
      q4[i] = q;
    }
  }
  if (tid < 144) qw[tid / 9][tid % 9] = quantq(cw[tid], sw);
  if (tid < 16) bias[tid] = cb[tid];
  __syncthreads();
  float lmax = 0.f;
  if (tid < nimg * 36) {
    const int img = tid / 36, pp = tid % 36, pi = pp / 6, pj = pp % 6;
    const float* base = &qx[img * 784 + pi * 4 * 28 + pj * 4];
    float r[36];
#pragma unroll
    for (int rr = 0; rr < 6; ++rr)
#pragma unroll
      for (int cc = 0; cc < 6; ++cc) r[rr * 6 + cc] = base[rr * 28 + cc];
    float* fo = &flat[(b0 + img) * 576 + pp];
#pragma unroll
    for (int c = 0; c < 16; ++c) {
      const float w0 = qw[c][0], w1 = qw[c][1], w2 = qw[c][2];
      const float w3 = qw[c][3], w4 = qw[c][4], w5 = qw[c][5];
      const float w6 = qw[c][6], w7 = qw[c][7], w8 = qw[c][8];
      const float bc = bias[c];
      float m = 0.f;
#pragma unroll
      for (int dr = 0; dr < 4; ++dr)
#pragma unroll
        for (int dc = 0; dc < 4; ++dc) {
          const float* q = &r[dr * 6 + dc];
          float acc = q[0] * w0 + q[1] * w1 + q[2] * w2
                    + q[6] * w3 + q[7] * w4 + q[8] * w5
                    + q[12] * w6 + q[13] * w7 + q[14] * w8;
          m = fmaxf(m, acc * sxw + bc);
        }
      fo[c * 36] = m;
      lmax = fmaxf(lmax, m);  // m >= 0
    }
  }
  lmax = block_reduce_max(lmax, smem);
  if (tid == 0) atomicMax(scal + 3, __float_as_uint(lmax));
}

// One WAVE per image (2048 blocks x 4 waves). Lanes read flat coalesced
// (k = j*64 + lane); quantized fc_w staged in LDS; butterfly reduce the 10
// accumulators. Integer dot (<= 28224) exact in f32.
__global__ __launch_bounds__(256) void fc_kernel(
    const float* __restrict__ flat, const float* __restrict__ fw,
    const float* __restrict__ fb, const unsigned int* __restrict__ scal,
    float* __restrict__ out) {
  __shared__ float qfw[5760];
  __shared__ float sb[10];
  const float sf = __uint_as_float(scal[3]) / 7.0f + 1e-8f;
  const float sfw = __uint_as_float(scal[2]) / 7.0f + 1e-8f;
  const int tid = threadIdx.x;
  for (int i = tid; i < 5760; i += 256) qfw[i] = quantq(fw[i], sfw);
  if (tid < 10) sb[tid] = fb[tid];
  __syncthreads();
  const int wave = tid >> 6, lane = tid & 63;
  const int b = blockIdx.x * 4 + wave;
  float acc[10];
#pragma unroll
  for (int o = 0; o < 10; ++o) acc[o] = 0.f;
  const float* frow = &flat[b * 576];
#pragma unroll
  for (int j = 0; j < 9; ++j) {
    const int k = j * 64 + lane;
    const float qf = quantq(frow[k], sf);
#pragma unroll
    for (int o = 0; o < 10; ++o) acc[o] += qf * qfw[o * 576 + k];
  }
#pragma unroll
  for (int o = 0; o < 10; ++o)
#pragma unroll
    for (int off = 32; off > 0; off >>= 1)
      acc[o] += __shfl_xor(acc[o], off, 64);
  if (lane == 0) {
    const float ss = sf * sfw;
#pragma unroll
    for (int o = 0; o < 10; ++o) out[b * 10 + o] = acc[o] * ss + sb[o];
  }
}

extern "C" void kernel_launch(void* const* d_in, const int* in_sizes, int n_in,
                              void* d_out, int out_size, void* d_ws, size_t ws_size,
                              hipStream_t stream) {
  const float* x  = (const float*)d_in[0];
  const float* cw = (const float*)d_in[1];
  const float* cb = (const float*)d_in[2];
  const float* fw = (const float*)d_in[3];
  const float* fb = (const float*)d_in[4];
  float* out = (float*)d_out;
  unsigned int* scal = (unsigned int*)d_ws;
  float* flat = (float*)((char*)d_ws + 256);

  prep_kernel<<<1, 256, 0, stream>>>(cw, fw, scal);
  maxabs_x_kernel<<<1024, 256, 0, stream>>>(
      (const float4*)x, (8192 * 784) / 4, scal);
  conv_pool_kernel<<<(8192 + IMGS_PER_BLK - 1) / IMGS_PER_BLK, 256, 0, stream>>>(
      x, cw, cb, scal, flat);
  fc_kernel<<<2048, 256, 0, stream>>>(flat, fw, fb, scal, out);
}